// Round 9
// baseline (2771.104 us; speedup 1.0000x reference)
//
#include <hip/hip_runtime.h>
#include <math.h>

#define H 1024
#define V 32000
#define B 256
#define S 64
#define T 10

#define GBK 32
#define NWG 256

typedef __attribute__((ext_vector_type(8))) short bf16x8;
typedef __attribute__((ext_vector_type(4))) float f32x4;

static __device__ __forceinline__ unsigned short f2bf(float f) {
  unsigned int u = __float_as_uint(f);
  u += 0x7fff + ((u >> 16) & 1);   // round-to-nearest-even
  return (unsigned short)(u >> 16);
}
static __device__ __forceinline__ float bf2f(unsigned short u) {
  return __uint_as_float(((unsigned int)u) << 16);
}
static __device__ __forceinline__ float fast_tanh(float x) {
  float e = __expf(2.f * x);
  return 1.f - 2.f * __builtin_amdgcn_rcpf(e + 1.f);
}
static __device__ __forceinline__ float fast_sigmoid(float x) {
  return __builtin_amdgcn_rcpf(1.f + __expf(-x));
}

static __device__ __forceinline__ void load_lds16(const void* g, void* l) {
  __builtin_amdgcn_global_load_lds(
      (const __attribute__((address_space(1))) unsigned int*)g,
      (__attribute__((address_space(3))) unsigned int*)l, 16, 0, 0);
}

// swizzled element offset within one LDS tile: row stride 32 elems (64 B).
static __device__ __forceinline__ int lds_off(int row, int g) {
  return row * GBK + ((g ^ ((row >> 1) & 3)) * 8);
}

// ---------------------------------------------------------------------------
// device-scope grid barrier (all NWG workgroups co-resident by construction:
// 256 WGs x 256 thr, <=33KB LDS -> >=4 WGs/CU capacity on 256 CUs).
// cnt self-resets to 0; gen monotonic. Both zeroed per kernel_launch call.
// ---------------------------------------------------------------------------
static __device__ __forceinline__ void gbar(unsigned* cnt, unsigned* gen) {
  __syncthreads();  // compiler drains vmcnt/lgkmcnt before s_barrier
  if (threadIdx.x == 0) {
    __threadfence();  // agent-scope release of this WG's writes
    unsigned g =
        __hip_atomic_load(gen, __ATOMIC_ACQUIRE, __HIP_MEMORY_SCOPE_AGENT);
    unsigned a = __hip_atomic_fetch_add(cnt, 1u, __ATOMIC_ACQ_REL,
                                        __HIP_MEMORY_SCOPE_AGENT);
    if (a == NWG - 1) {
      __hip_atomic_store(cnt, 0u, __ATOMIC_RELAXED, __HIP_MEMORY_SCOPE_AGENT);
      __hip_atomic_fetch_add(gen, 1u, __ATOMIC_ACQ_REL,
                             __HIP_MEMORY_SCOPE_AGENT);
    } else {
      while (__hip_atomic_load(gen, __ATOMIC_ACQUIRE,
                               __HIP_MEMORY_SCOPE_AGENT) == g)
        __builtin_amdgcn_s_sleep(8);
    }
    __threadfence();  // agent-scope acquire for this WG's subsequent reads
  }
  __syncthreads();
}

// ---------------------------------------------------------------------------
// 64x64-tile GEMM phase body (K=H, 4 waves of 32x32, 3-stage counted pipeline)
// MODE 0: C = acc + aux[col]     MODE 2: C = acc + aux[row*ldc+col]
// ---------------------------------------------------------------------------
template <int MODE>
static __device__ void gemm64_dev(
    const unsigned short* __restrict__ A, const unsigned short* __restrict__ W,
    const float* __restrict__ aux, float* __restrict__ C, int ldc,
    int mBase, int nBase,
    unsigned short (&lsA)[3][64 * GBK], unsigned short (&lsB)[3][64 * GBK]) {
  const int tid = threadIdx.x;
  const int lane = tid & 63;
  const int w = tid >> 6;
  const int rowBase = (w >> 1) * 32;
  const int colBase = (w & 1) * 32;
  const int fr = lane & 15;
  const int fkU = lane >> 4;
  const int fg = lane >> 4;

  f32x4 acc[2][2] = {};

  auto STAGE = [&](int buf, int k0) {
    int row = tid >> 2;
    int u = tid & 3;
    int col = (u ^ ((row >> 1) & 3)) * 8;
    load_lds16(A + (size_t)(mBase + row) * H + k0 + col, &lsA[buf][tid * 8]);
    load_lds16(W + (size_t)(nBase + row) * H + k0 + col, &lsB[buf][tid * 8]);
  };

  // other phases' loads/stores share the vmcnt counter -> drain first
  asm volatile("s_waitcnt vmcnt(0)" ::: "memory");
  const int NT = H / GBK;
  STAGE(0, 0);
  STAGE(1, GBK);
  int cb = 0;
  for (int t = 0; t < NT; ++t) {
    if (t + 1 < NT) {
      asm volatile("s_waitcnt vmcnt(2)\n\ts_barrier" ::: "memory");
    } else {
      asm volatile("s_waitcnt vmcnt(0)\n\ts_barrier" ::: "memory");
    }
    if (t + 2 < NT) STAGE((cb + 2) % 3, (t + 2) * GBK);

    bf16x8 af[2], bfr[2];
#pragma unroll
    for (int m = 0; m < 2; ++m)
      af[m] = *(const bf16x8*)&lsA[cb][lds_off(rowBase + m * 16 + fr, fkU)];
#pragma unroll
    for (int n = 0; n < 2; ++n)
      bfr[n] = *(const bf16x8*)&lsB[cb][lds_off(colBase + n * 16 + fr, fkU)];
#pragma unroll
    for (int m = 0; m < 2; ++m)
#pragma unroll
      for (int n = 0; n < 2; ++n)
        acc[m][n] = __builtin_amdgcn_mfma_f32_16x16x32_bf16(
            af[m], bfr[n], acc[m][n], 0, 0, 0);
    cb = (cb + 1) % 3;
  }

#pragma unroll
  for (int m = 0; m < 2; ++m)
#pragma unroll
    for (int n = 0; n < 2; ++n) {
      const int colg = nBase + colBase + n * 16 + fr;
#pragma unroll
      for (int r = 0; r < 4; ++r) {
        const int rowg = mBase + rowBase + m * 16 + fg * 4 + r;
        float v;
        if constexpr (MODE == 2)
          v = acc[m][n][r] + aux[(size_t)rowg * ldc + colg];
        else
          v = acc[m][n][r] + aux[colg];
        C[(size_t)rowg * ldc + colg] = v;
      }
    }
}

// ---------------------------------------------------------------------------
// Persistent recurrent-loop kernel: all T steps, 4 phases/step, grid barriers.
// grid = NWG(256) x 256 threads.
// ---------------------------------------------------------------------------
__global__ __launch_bounds__(256) void decoder_loop_kernel(
    unsigned short* __restrict__ hAll,        // [(T+1), B, H] bf16; slot0 = enc
    const unsigned short* __restrict__ fusedW,  // [4H, H]
    const float* __restrict__ fusedB,           // [4H]
    const unsigned short* __restrict__ Uk_bf,   // [B,S,H]
    const unsigned short* __restrict__ keys_bf, // [B,S,H]
    const float* __restrict__ Va_w, const float* __restrict__ Va_b,
    const unsigned short* __restrict__ Wctx_bf, // [3H, H]
    const float* __restrict__ giE,              // [T,B,3H]
    const float* __restrict__ enc_hidden,       // [B,H] fp32
    float* __restrict__ hA, float* __restrict__ hB,
    float* __restrict__ wqgh,                   // [B,4H]
    unsigned short* __restrict__ ctx_bf,        // [B,H]
    float* __restrict__ gi,                     // [B,3H]
    float* __restrict__ out_attn,               // [B,T,S]
    float* __restrict__ out_h,                  // [B,H]
    unsigned* __restrict__ bar) {               // [2]: cnt, gen
  __shared__ unsigned short lsA[3][64 * GBK];   // 12 KB
  __shared__ unsigned short lsB[3][64 * GBK];   // 12 KB
  __shared__ float wqs[H];                      // 4 KB
  __shared__ float vas[H];                      // 4 KB
  __shared__ float sw[S];

  const int g = blockIdx.x;
  const int tid = threadIdx.x;
  unsigned* cnt = bar;
  unsigned* gen = bar + 1;

  for (int t = 0; t < T; ++t) {
    const unsigned short* hbf_in = hAll + (size_t)t * B * H;
    unsigned short* hbf_out = hAll + (size_t)(t + 1) * B * H;
    const float* h_in = (t == 0) ? enc_hidden : ((t & 1) ? hA : hB);
    float* h_out = (t & 1) ? hB : hA;

    // ---- Phase A: wqgh = h @ [Wa_w; w_hh]^T + [Wa_b; b_hh]  (4 x 64 tiles)
    gemm64_dev<0>(hbf_in, fusedW, fusedB, wqgh, 4 * H, (g & 3) * 64,
                  (g >> 2) * 64, lsA, lsB);
    gbar(cnt, gen);

    // ---- Phase B: attention for b = g
    {
      const int b = g;
      ((float4*)wqs)[tid] = ((const float4*)(wqgh + (size_t)b * 4 * H))[tid];
      ((float4*)vas)[tid] = ((const float4*)Va_w)[tid];
      __syncthreads();

      const int s = tid >> 2;
      const int hc = (tid & 3) * 256;
      const unsigned short* uk = Uk_bf + ((size_t)b * S + s) * H + hc;
      float sum = 0.f;
#pragma unroll 4
      for (int i = 0; i < 256; i += 8) {
        bf16x8 u = *(const bf16x8*)&uk[i];
#pragma unroll
        for (int j = 0; j < 8; ++j) {
          float e = fast_tanh(wqs[hc + i + j] + bf2f((unsigned short)u[j]));
          sum += e * vas[hc + i + j];
        }
      }
      sum += __shfl_xor(sum, 1, 64);
      sum += __shfl_xor(sum, 2, 64);
      if ((tid & 3) == 0) sw[s] = sum + Va_b[0];
      __syncthreads();

      if (tid < 64) {
        float v = sw[tid];
        float m = v;
        for (int off = 32; off > 0; off >>= 1)
          m = fmaxf(m, __shfl_xor(m, off, 64));
        float e = __expf(v - m);
        float sm = e;
        for (int off = 32; off > 0; off >>= 1) sm += __shfl_xor(sm, off, 64);
        float wv = e / sm;
        sw[tid] = wv;
        out_attn[((size_t)b * T + t) * S + tid] = wv;
      }
      __syncthreads();

      const unsigned short* kb = keys_bf + (size_t)b * S * H + tid * 4;
      float c0 = 0.f, c1 = 0.f, c2 = 0.f, c3 = 0.f;
#pragma unroll 8
      for (int s2 = 0; s2 < S; ++s2) {
        float wv = sw[s2];
        ushort4 kv = *(const ushort4*)&kb[(size_t)s2 * H];
        c0 += wv * bf2f(kv.x);
        c1 += wv * bf2f(kv.y);
        c2 += wv * bf2f(kv.z);
        c3 += wv * bf2f(kv.w);
      }
      ushort4 o;
      o.x = f2bf(c0); o.y = f2bf(c1); o.z = f2bf(c2); o.w = f2bf(c3);
      *(ushort4*)&ctx_bf[(size_t)b * H + tid * 4] = o;
    }
    gbar(cnt, gen);

    // ---- Phase C: gi = giE[t] + ctx @ Wctx^T  (4 x 48 tiles, 192 WGs)
    if (g < 192) {
      gemm64_dev<2>(ctx_bf, Wctx_bf, giE + (size_t)t * B * 3 * H, gi, 3 * H,
                    (g & 3) * 64, (g >> 2) * 64, lsA, lsB);
    }
    gbar(cnt, gen);

    // ---- Phase D: GRU combine; 4 consecutive elems per thread
    {
      const int idx = (g * 256 + tid) * 4;   // < B*H = 262144
      const int b = idx >> 10;
      const int j = idx & (H - 1);
      const float* gib = gi + (size_t)b * 3 * H;
      const float* ghb = wqgh + (size_t)b * 4 * H + H;
      float4 gr4 = *(const float4*)&gib[j];
      float4 gz4 = *(const float4*)&gib[H + j];
      float4 gn4 = *(const float4*)&gib[2 * H + j];
      float4 hr4 = *(const float4*)&ghb[j];
      float4 hz4 = *(const float4*)&ghb[H + j];
      float4 hn4 = *(const float4*)&ghb[2 * H + j];
      float4 hp4 = *(const float4*)&h_in[idx];
      float4 ho4;
      ushort4 hb4;
      {
        float r0 = fast_sigmoid(gr4.x + hr4.x);
        float z0 = fast_sigmoid(gz4.x + hz4.x);
        float n0 = fast_tanh(gn4.x + r0 * hn4.x);
        ho4.x = (1.f - z0) * n0 + z0 * hp4.x;
        float r1 = fast_sigmoid(gr4.y + hr4.y);
        float z1 = fast_sigmoid(gz4.y + hz4.y);
        float n1 = fast_tanh(gn4.y + r1 * hn4.y);
        ho4.y = (1.f - z1) * n1 + z1 * hp4.y;
        float r2 = fast_sigmoid(gr4.z + hr4.z);
        float z2 = fast_sigmoid(gz4.z + hz4.z);
        float n2 = fast_tanh(gn4.z + r2 * hn4.z);
        ho4.z = (1.f - z2) * n2 + z2 * hp4.z;
        float r3 = fast_sigmoid(gr4.w + hr4.w);
        float z3 = fast_sigmoid(gz4.w + hz4.w);
        float n3 = fast_tanh(gn4.w + r3 * hn4.w);
        ho4.w = (1.f - z3) * n3 + z3 * hp4.w;
      }
      hb4.x = f2bf(ho4.x); hb4.y = f2bf(ho4.y);
      hb4.z = f2bf(ho4.z); hb4.w = f2bf(ho4.w);
      *(float4*)&h_out[idx] = ho4;
      *(ushort4*)&hbf_out[idx] = hb4;
      if (t == T - 1) *(float4*)&out_h[idx] = ho4;
    }
    gbar(cnt, gen);
  }
}

// ---------------------------------------------------------------------------
// bf16 MFMA GEMM (standalone), TMxTN tile, BK=32, 4 waves, STAGES pipeline.
// ---------------------------------------------------------------------------
template <int TM, int TN, int MODE, int GRIDMODE, int STAGES>
__global__ __launch_bounds__(256) void gemm_mfma(
    const unsigned short* __restrict__ A, const unsigned short* __restrict__ W,
    const float* __restrict__ aux, float* __restrict__ C,
    unsigned short* __restrict__ Cb, float* __restrict__ partials,
    int M, int N, int K, int ldc, int pstride) {
  constexpr int FM = (TM == 128) ? 4 : 2;
  constexpr int FN = (TN == 128) ? 4 : 2;
  constexpr int CA = TM / 64;
  constexpr int CB = TN / 64;
  constexpr int LOADS = CA + CB;

  __shared__ unsigned short lsA[STAGES][TM * GBK];
  __shared__ unsigned short lsB[STAGES][TN * GBK];
  const int tid = threadIdx.x;
  const int lane = tid & 63;
  const int w = tid >> 6;

  int mIdx, nIdx;
  if constexpr (GRIDMODE == 1) {
    const int nwg = gridDim.x * gridDim.y;
    const int orig = blockIdx.y * gridDim.x + blockIdx.x;
    const int q = nwg >> 3, rr = nwg & 7;
    const int xcd = orig & 7, rest = orig >> 3;
    const int wgid =
        (xcd < rr ? xcd * (q + 1) : rr * (q + 1) + (xcd - rr) * q) + rest;
    mIdx = wgid % gridDim.x;
    nIdx = wgid / gridDim.x;
  } else {
    mIdx = blockIdx.y;
    nIdx = blockIdx.x;
  }
  const int mBase = mIdx * TM;
  const int nBase = nIdx * TN;
  const int rowBase = (w >> 1) * (TM / 2);
  const int colBase = (w & 1) * (TN / 2);

  const int fr = lane & 15;
  const int fkU = lane >> 4;
  const int fg = lane >> 4;

  f32x4 acc[FM][FN] = {};

  auto STAGE = [&](int buf, int k0) {
#pragma unroll
    for (int i = 0; i < CA; ++i) {
      int chunk = i * 256 + tid;
      int row = chunk >> 2;
      int u = chunk & 3;
      int col = (u ^ ((row >> 1) & 3)) * 8;
      load_lds16(A + (size_t)(mBase + row) * K + k0 + col,
                 &lsA[buf][chunk * 8]);
    }
#pragma unroll
    for (int i = 0; i < CB; ++i) {
      int chunk = i * 256 + tid;
      int row = chunk >> 2;
      int u = chunk & 3;
      int col = (u ^ ((row >> 1) & 3)) * 8;
      load_lds16(W + (size_t)(nBase + row) * K + k0 + col,
                 &lsB[buf][chunk * 8]);
    }
  };

  const int NT = K / GBK;
  STAGE(0, 0);
  if constexpr (STAGES == 3) STAGE(1, GBK);
  int cb = 0;
  for (int t = 0; t < NT; ++t) {
    if constexpr (STAGES == 3) {
      if (t + 1 < NT) {
        asm volatile("s_waitcnt vmcnt(%0)\n\ts_barrier" :: "i"(LOADS)
                     : "memory");
      } else {
        asm volatile("s_waitcnt vmcnt(0)\n\ts_barrier" ::: "memory");
      }
      if (t + 2 < NT) STAGE((cb + 2) % 3, (t + 2) * GBK);
    } else {
      asm volatile("s_waitcnt vmcnt(0)\n\ts_barrier" ::: "memory");
      if (t + 1 < NT) STAGE(cb ^ 1, (t + 1) * GBK);
    }

    bf16x8 af[FM], bfr[FN];
#pragma unroll
    for (int m = 0; m < FM; ++m)
      af[m] = *(const bf16x8*)&lsA[cb][lds_off(rowBase + m * 16 + fr, fkU)];
#pragma unroll
    for (int n = 0; n < FN; ++n)
      bfr[n] = *(const bf16x8*)&lsB[cb][lds_off(colBase + n * 16 + fr, fkU)];
#pragma unroll
    for (int m = 0; m < FM; ++m)
#pragma unroll
      for (int n = 0; n < FN; ++n)
        acc[m][n] = __builtin_amdgcn_mfma_f32_16x16x32_bf16(
            af[m], bfr[n], acc[m][n], 0, 0, 0);
    cb = (STAGES == 3) ? (cb + 1) % 3 : (cb ^ 1);
  }

#pragma unroll
  for (int m = 0; m < FM; ++m) {
    int colg[FN];
    float bv[FN];
#pragma unroll
    for (int n = 0; n < FN; ++n) {
      colg[n] = nBase + colBase + n * 16 + fr;
      if constexpr (MODE != 2) bv[n] = aux[colg[n]];
    }
#pragma unroll
    for (int r = 0; r < 4; ++r) {
      const int rowg = mBase + rowBase + m * 16 + fg * 4 + r;
      float v[FN];
#pragma unroll
      for (int n = 0; n < FN; ++n) {
        if constexpr (MODE == 2)
          v[n] = acc[m][n][r] + aux[(size_t)rowg * ldc + colg[n]];
        else
          v[n] = acc[m][n][r] + bv[n];
        if constexpr (MODE == 1 || MODE == 3)
          Cb[(size_t)rowg * ldc + colg[n]] = f2bf(v[n]);
        else
          C[(size_t)rowg * ldc + colg[n]] = v[n];
      }
      if constexpr (MODE == 3) {
        float mx = fmaxf(fmaxf(v[0], v[1]), fmaxf(v[2], v[3]));
        mx = fmaxf(mx, __shfl_xor(mx, 1, 64));
        mx = fmaxf(mx, __shfl_xor(mx, 2, 64));
        mx = fmaxf(mx, __shfl_xor(mx, 4, 64));
        mx = fmaxf(mx, __shfl_xor(mx, 8, 64));
        float se = __expf(v[0] - mx) + __expf(v[1] - mx) +
                   __expf(v[2] - mx) + __expf(v[3] - mx);
        se += __shfl_xor(se, 1, 64);
        se += __shfl_xor(se, 2, 64);
        se += __shfl_xor(se, 4, 64);
        se += __shfl_xor(se, 8, 64);
        if (fr == 0) {
          float2* pp = (float2*)partials;
          pp[(size_t)rowg * pstride + nIdx * 2 + (w & 1)] =
              make_float2(mx, se);
        }
      }
    }
  }
}

// ---------------------------------------------------------------------------
__global__ __launch_bounds__(256) void cvt_bf16_kernel(
    const float* __restrict__ src, unsigned short* __restrict__ dst) {
  size_t i = ((size_t)blockIdx.x * 256 + threadIdx.x) * 8;
  float4 a = *(const float4*)&src[i];
  float4 b = *(const float4*)&src[i + 4];
  ushort4 lo, hi;
  lo.x = f2bf(a.x); lo.y = f2bf(a.y); lo.z = f2bf(a.z); lo.w = f2bf(a.w);
  hi.x = f2bf(b.x); hi.y = f2bf(b.y); hi.z = f2bf(b.z); hi.w = f2bf(b.w);
  *(ushort4*)&dst[i] = lo;
  *(ushort4*)&dst[i + 4] = hi;
}

__global__ __launch_bounds__(256) void cvt_split_wih(
    const float* __restrict__ w_ih, unsigned short* __restrict__ Wemb,
    unsigned short* __restrict__ Wctx) {
  size_t base = ((size_t)blockIdx.x * 256 + threadIdx.x) * 8;
  int row = (int)(base >> 11);
  int col = (int)(base & 2047);
  float4 a = *(const float4*)&w_ih[base];
  float4 b = *(const float4*)&w_ih[base + 4];
  ushort4 lo, hi;
  lo.x = f2bf(a.x); lo.y = f2bf(a.y); lo.z = f2bf(a.z); lo.w = f2bf(a.w);
  hi.x = f2bf(b.x); hi.y = f2bf(b.y); hi.z = f2bf(b.z); hi.w = f2bf(b.w);
  unsigned short* dst = (col < H) ? (Wemb + (size_t)row * H + col)
                                  : (Wctx + (size_t)row * H + col - H);
  *(ushort4*)dst = lo;
  *(ushort4*)(dst + 4) = hi;
}

__global__ __launch_bounds__(256) void build_fused_bias(
    const float* __restrict__ Wa_b, const float* __restrict__ b_hh,
    float* __restrict__ fb) {
  int i = blockIdx.x * 256 + threadIdx.x;
  fb[i] = (i < H) ? Wa_b[i] : b_hh[i - H];
}

__global__ __launch_bounds__(256) void embed_all_kernel(
    const int* __restrict__ target, const float* __restrict__ emb,
    unsigned short* __restrict__ embAll) {
  int idx = blockIdx.x * 256 + threadIdx.x;  // over T*B*(H/8)
  int h8 = (idx & 127) * 8;
  int tb = idx >> 7;
  int t = tb >> 8;
  int b = tb & 255;
  int tok = (t == 0) ? 0 : target[b * T + (t - 1)];
  const float* e = emb + (size_t)tok * H + h8;
  float4 a = *(const float4*)e;
  float4 c = *(const float4*)(e + 4);
  ushort4 lo, hi;
  lo.x = f2bf(a.x); lo.y = f2bf(a.y); lo.z = f2bf(a.z); lo.w = f2bf(a.w);
  hi.x = f2bf(c.x); hi.y = f2bf(c.y); hi.z = f2bf(c.z); hi.w = f2bf(c.w);
  unsigned short* d = embAll + (size_t)tb * H + h8;
  *(ushort4*)d = lo;
  *(ushort4*)(d + 4) = hi;
}

// ---------------------------------------------------------------------------
__global__ __launch_bounds__(256) void logsm_reduce_kernel(
    const float* __restrict__ partials, float* __restrict__ ls, int P) {
  const int row = blockIdx.x;
  const int tid = threadIdx.x;
  const float2* pp = (const float2*)partials + (size_t)row * P;
  __shared__ float red[256];
  float mx = -INFINITY;
  for (int i = tid; i < P; i += 256) mx = fmaxf(mx, pp[i].x);
  red[tid] = mx;
  __syncthreads();
  for (int off = 128; off > 0; off >>= 1) {
    if (tid < off) red[tid] = fmaxf(red[tid], red[tid + off]);
    __syncthreads();
  }
  mx = red[0];
  __syncthreads();
  float sm = 0.f;
  for (int i = tid; i < P; i += 256) sm += pp[i].y * __expf(pp[i].x - mx);
  red[tid] = sm;
  __syncthreads();
  for (int off = 128; off > 0; off >>= 1) {
    if (tid < off) red[tid] += red[tid + off];
    __syncthreads();
  }
  if (tid == 0) ls[row] = mx + __logf(red[0]);
}

// dec[b, t, :] = bf2f(logits_bf[tb, :]) - ls[tb];  tb = t*B + b
__global__ __launch_bounds__(256) void logsm_sub_kernel(
    const unsigned short* __restrict__ logits_bf, const float* __restrict__ ls,
    float* __restrict__ dec) {
  const int tb = blockIdx.y;
  const int t = tb >> 8;         // B = 256
  const int b = tb & 255;
  const int i8 = (blockIdx.x * 256 + threadIdx.x) * 8;
  if (i8 < V) {
    float l = ls[tb];
    const unsigned short* src = logits_bf + (size_t)tb * V + i8;
    bf16x8 u = *(const bf16x8*)src;
    float* d = dec + (size_t)b * T * V + (size_t)t * V + i8;
    float4 o0, o1;
    o0.x = bf2f((unsigned short)u[0]) - l; o0.y = bf2f((unsigned short)u[1]) - l;
    o0.z = bf2f((unsigned short)u[2]) - l; o0.w = bf2f((unsigned short)u[3]) - l;
    o1.x = bf2f((unsigned short)u[4]) - l; o1.y = bf2f((unsigned short)u[5]) - l;
    o1.z = bf2f((unsigned short)u[6]) - l; o1.w = bf2f((unsigned short)u[7]) - l;
    *(float4*)d = o0;
    *(float4*)(d + 4) = o1;
  }
}

// ---------------------------------------------------------------------------
extern "C" void kernel_launch(void* const* d_in, const int* in_sizes, int n_in,
                              void* d_out, int out_size, void* d_ws, size_t ws_size,
                              hipStream_t stream) {
  const float* keys       = (const float*)d_in[0];
  const float* enc_hidden = (const float*)d_in[1];
  const int*   target     = (const int*)d_in[2];
  const float* embedding  = (const float*)d_in[3];
  const float* Wa_w = (const float*)d_in[4];
  const float* Wa_b = (const float*)d_in[5];
  const float* Ua_w = (const float*)d_in[6];
  const float* Ua_b = (const float*)d_in[7];
  const float* Va_w = (const float*)d_in[8];
  const float* Va_b = (const float*)d_in[9];
  const float* gru_w_ih = (const float*)d_in[10];
  const float* gru_w_hh = (const float*)d_in[11];
  const float* gru_b_ih = (const float*)d_in[12];
  const float* gru_b_hh = (const float*)d_in[13];
  const float* out_w = (const float*)d_in[14];
  const float* out_b = (const float*)d_in[15];

  float* out = (float*)d_out;
  float* out_dec  = out;
  float* out_h    = out + (size_t)B * T * V;
  float* out_attn = out + (size_t)B * T * V + (size_t)B * H;

  // ---- workspace ----
  char* p = (char*)d_ws;
  unsigned short* keys_bf = (unsigned short*)p; p += (size_t)B * S * H * 2;
  unsigned short* outw_bf = (unsigned short*)p; p += (size_t)V * H * 2;
  unsigned short* Uaw_bf  = (unsigned short*)p; p += (size_t)H * H * 2;
  unsigned short* fusedW  = (unsigned short*)p; p += (size_t)4 * H * H * 2;
  float*          fusedB  = (float*)p;          p += (size_t)4 * H * 4;
  unsigned short* Wemb_bf = (unsigned short*)p; p += (size_t)3 * H * H * 2;
  unsigned short* Wctx_bf = (unsigned short*)p; p += (size_t)3 * H * H * 2;
  unsigned short* embAll  = (unsigned short*)p; p += (size_t)T * B * H * 2;
  unsigned short* Uk_bf   = (unsigned short*)p; p += (size_t)B * S * H * 2;
  float*          giE     = (float*)p;          p += (size_t)T * B * 3 * H * 4;
  float*          wqgh    = (float*)p;          p += (size_t)B * 4 * H * 4;
  unsigned short* ctx_bf  = (unsigned short*)p; p += (size_t)B * H * 2;
  float*          gi      = (float*)p;          p += (size_t)B * 3 * H * 4;
  float*          hA      = (float*)p;          p += (size_t)B * H * 4;
  float*          hB      = (float*)p;          p += (size_t)B * H * 4;
  unsigned short* hAll    = (unsigned short*)p; p += (size_t)(T + 1) * B * H * 2;
  unsigned short* logits_bf = (unsigned short*)p; p += (size_t)T * B * V * 2;
  float*          parts   = (float*)p;          p += (size_t)T * B * 500 * 2 * 4;
  float*          ls      = (float*)p;          p += (size_t)T * B * 4;
  unsigned*       barrier = (unsigned*)p;       p += 256;

  // barrier state must be zero at kernel start (deterministic per call)
  hipMemsetAsync(barrier, 0, 256, stream);

  // ---- one-time prep ----
  cvt_bf16_kernel<<<(B * S * H) / 2048, 256, 0, stream>>>(keys, keys_bf);
  cvt_bf16_kernel<<<((size_t)V * H) / 2048, 256, 0, stream>>>(out_w, outw_bf);
  cvt_bf16_kernel<<<(H * H) / 2048, 256, 0, stream>>>(Ua_w, Uaw_bf);
  cvt_bf16_kernel<<<(H * H) / 2048, 256, 0, stream>>>(Wa_w, fusedW);
  cvt_bf16_kernel<<<(3 * H * H) / 2048, 256, 0, stream>>>(gru_w_hh,
                                                          fusedW + (size_t)H * H);
  build_fused_bias<<<(4 * H) / 256, 256, 0, stream>>>(Wa_b, gru_b_hh, fusedB);
  cvt_split_wih<<<(3 * H * 2 * H) / 2048, 256, 0, stream>>>(gru_w_ih, Wemb_bf,
                                                            Wctx_bf);
  embed_all_kernel<<<(T * B * H / 8) / 256, 256, 0, stream>>>(target, embedding,
                                                              embAll);
  cvt_bf16_kernel<<<(B * H) / 2048, 256, 0, stream>>>(enc_hidden, hAll);

  // Uk_bf = bf16(keys @ Ua_w^T + Ua_b)
  gemm_mfma<128, 128, 1, 0, 2>
      <<<dim3(H / 128, (B * S) / 128), 256, 0, stream>>>(
          keys_bf, Uaw_bf, Ua_b, nullptr, Uk_bf, nullptr, B * S, H, H, H, 0);
  // giE = embAll @ Wemb^T + b_ih
  gemm_mfma<128, 128, 0, 1, 2>
      <<<dim3((T * B) / 128, 3 * H / 128), 256, 0, stream>>>(
          embAll, Wemb_bf, gru_b_ih, giE, nullptr, nullptr, T * B, 3 * H, H,
          3 * H, 0);

  // ---- the entire recurrent loop: one persistent kernel ----
  decoder_loop_kernel<<<NWG, 256, 0, stream>>>(
      hAll, fusedW, fusedB, Uk_bf, keys_bf, Va_w, Va_b, Wctx_bf, giE,
      enc_hidden, hA, hB, wqgh, ctx_bf, gi, out_attn, out_h, barrier);

  // batched vocab projection over all steps: A rows tb = t*B + b -> h_{t+1}
  gemm_mfma<128, 128, 3, 1, 2>
      <<<dim3((T * B) / 128, V / 128), 256, 0, stream>>>(
          hAll + (size_t)B * H, outw_bf, out_b, nullptr, logits_bf, parts,
          T * B, V, H, V, 500);
  logsm_reduce_kernel<<<T * B, 256, 0, stream>>>(parts, ls, 500);
  logsm_sub_kernel<<<dim3((V + 2047) / 2048, T * B), 256, 0, stream>>>(
      logits_bf, ls, out_dec);
}

// Round 10
// 1215.377 us; speedup vs baseline: 2.2800x; 2.2800x over previous
//
#include <hip/hip_runtime.h>
#include <math.h>

#define H 1024
#define V 32000
#define B 256
#define S 64
#define T 10

#define GBK 32

typedef __attribute__((ext_vector_type(8))) short bf16x8;
typedef __attribute__((ext_vector_type(4))) float f32x4;

static __device__ __forceinline__ unsigned short f2bf(float f) {
  unsigned int u = __float_as_uint(f);
  u += 0x7fff + ((u >> 16) & 1);   // round-to-nearest-even
  return (unsigned short)(u >> 16);
}
static __device__ __forceinline__ float bf2f(unsigned short u) {
  return __uint_as_float(((unsigned int)u) << 16);
}
static __device__ __forceinline__ float fast_tanh(float x) {
  float e = __expf(2.f * x);
  return 1.f - 2.f * __builtin_amdgcn_rcpf(e + 1.f);
}
static __device__ __forceinline__ float fast_sigmoid(float x) {
  return __builtin_amdgcn_rcpf(1.f + __expf(-x));
}

static __device__ __forceinline__ void load_lds16(const void* g, void* l) {
  __builtin_amdgcn_global_load_lds(
      (const __attribute__((address_space(1))) unsigned int*)g,
      (__attribute__((address_space(3))) unsigned int*)l, 16, 0, 0);
}

// swizzled element offset within one LDS tile: row stride 32 elems (64 B).
static __device__ __forceinline__ int lds_off(int row, int g) {
  return row * GBK + ((g ^ ((row >> 1) & 3)) * 8);
}

// ---------------------------------------------------------------------------
// bf16 MFMA GEMM, TMxTN tile, BK=32, 4 waves (2x2), STAGES-deep pipeline with
// counted vmcnt + raw barrier.  C = A @ W^T (+ epilogue).
// TM in {64,128,256}, TN in {64,128}.  FM=TM/32 m-frags, FN=TN/32 n-frags/wave.
// GRIDMODE 0: grid (N/TN, M/TM).
// GRIDMODE 1: grid (M/TM, N/TN) + bijective XCD swizzle (m204): each XCD owns
//   a contiguous chunk of N-panels, M varies fastest -> W panel L2-resident.
// MODE 0: C fp32 = acc + bias[col]
// MODE 1: Cb bf16 = acc + bias[col]
// MODE 2: C fp32 = acc + aux[row*ldc + col]
// MODE 3: Cb bf16 = acc + bias[col]; per-row (max,sumexp) partials ->
//         partials[row][nIdx*2 + (w&1)]                (TN=128 only)
// ---------------------------------------------------------------------------
template <int TM, int TN, int MODE, int GRIDMODE, int STAGES>
__global__ __launch_bounds__(256) void gemm_mfma(
    const unsigned short* __restrict__ A, const unsigned short* __restrict__ W,
    const float* __restrict__ aux, float* __restrict__ C,
    unsigned short* __restrict__ Cb, float* __restrict__ partials,
    int M, int N, int K, int ldc, int pstride) {
  constexpr int FM = TM / 32;
  constexpr int FN = TN / 32;
  constexpr int CA = TM / 64;
  constexpr int CB = TN / 64;
  constexpr int LOADS = CA + CB;

  __shared__ unsigned short lsA[STAGES][TM * GBK];
  __shared__ unsigned short lsB[STAGES][TN * GBK];
  const int tid = threadIdx.x;
  const int lane = tid & 63;
  const int w = tid >> 6;

  int mIdx, nIdx;
  if constexpr (GRIDMODE == 1) {
    const int nwg = gridDim.x * gridDim.y;
    const int orig = blockIdx.y * gridDim.x + blockIdx.x;
    const int q = nwg >> 3, rr = nwg & 7;
    const int xcd = orig & 7, rest = orig >> 3;
    const int wgid =
        (xcd < rr ? xcd * (q + 1) : rr * (q + 1) + (xcd - rr) * q) + rest;
    mIdx = wgid % gridDim.x;
    nIdx = wgid / gridDim.x;
  } else {
    mIdx = blockIdx.y;
    nIdx = blockIdx.x;
  }
  const int mBase = mIdx * TM;
  const int nBase = nIdx * TN;
  const int rowBase = (w >> 1) * (TM / 2);
  const int colBase = (w & 1) * (TN / 2);

  const int fr = lane & 15;
  const int fkU = lane >> 4;
  const int fg = lane >> 4;

  f32x4 acc[FM][FN] = {};

  auto STAGE = [&](int buf, int k0) {
#pragma unroll
    for (int i = 0; i < CA; ++i) {
      int chunk = i * 256 + tid;
      int row = chunk >> 2;
      int u = chunk & 3;
      int col = (u ^ ((row >> 1) & 3)) * 8;
      load_lds16(A + (size_t)(mBase + row) * K + k0 + col,
                 &lsA[buf][chunk * 8]);
    }
#pragma unroll
    for (int i = 0; i < CB; ++i) {
      int chunk = i * 256 + tid;
      int row = chunk >> 2;
      int u = chunk & 3;
      int col = (u ^ ((row >> 1) & 3)) * 8;
      load_lds16(W + (size_t)(nBase + row) * K + k0 + col,
                 &lsB[buf][chunk * 8]);
    }
  };

  const int NT = K / GBK;
  STAGE(0, 0);
  if constexpr (STAGES == 3) STAGE(1, GBK);
  int cb = 0;
  for (int t = 0; t < NT; ++t) {
    if constexpr (STAGES == 3) {
      if (t + 1 < NT) {
        asm volatile("s_waitcnt vmcnt(%0)\n\ts_barrier" :: "i"(LOADS)
                     : "memory");
      } else {
        asm volatile("s_waitcnt vmcnt(0)\n\ts_barrier" ::: "memory");
      }
      if (t + 2 < NT) STAGE((cb + 2) % 3, (t + 2) * GBK);
    } else {
      asm volatile("s_waitcnt vmcnt(0)\n\ts_barrier" ::: "memory");
      if (t + 1 < NT) STAGE(cb ^ 1, (t + 1) * GBK);
    }

    bf16x8 af[FM], bfr[FN];
#pragma unroll
    for (int m = 0; m < FM; ++m)
      af[m] = *(const bf16x8*)&lsA[cb][lds_off(rowBase + m * 16 + fr, fkU)];
#pragma unroll
    for (int n = 0; n < FN; ++n)
      bfr[n] = *(const bf16x8*)&lsB[cb][lds_off(colBase + n * 16 + fr, fkU)];
#pragma unroll
    for (int m = 0; m < FM; ++m)
#pragma unroll
      for (int n = 0; n < FN; ++n)
        acc[m][n] = __builtin_amdgcn_mfma_f32_16x16x32_bf16(
            af[m], bfr[n], acc[m][n], 0, 0, 0);
    cb = (STAGES == 3) ? (cb + 1) % 3 : (cb ^ 1);
  }

#pragma unroll
  for (int m = 0; m < FM; ++m) {
    int colg[FN];
    float bv[FN];
#pragma unroll
    for (int n = 0; n < FN; ++n) {
      colg[n] = nBase + colBase + n * 16 + fr;
      if constexpr (MODE != 2) bv[n] = aux[colg[n]];
    }
#pragma unroll
    for (int r = 0; r < 4; ++r) {
      const int rowg = mBase + rowBase + m * 16 + fg * 4 + r;
      float v[FN];
#pragma unroll
      for (int n = 0; n < FN; ++n) {
        if constexpr (MODE == 2)
          v[n] = acc[m][n][r] + aux[(size_t)rowg * ldc + colg[n]];
        else
          v[n] = acc[m][n][r] + bv[n];
        if constexpr (MODE == 1 || MODE == 3)
          Cb[(size_t)rowg * ldc + colg[n]] = f2bf(v[n]);
        else
          C[(size_t)rowg * ldc + colg[n]] = v[n];
      }
      if constexpr (MODE == 3) {
        float mx = fmaxf(fmaxf(v[0], v[1]), fmaxf(v[2], v[3]));
        mx = fmaxf(mx, __shfl_xor(mx, 1, 64));
        mx = fmaxf(mx, __shfl_xor(mx, 2, 64));
        mx = fmaxf(mx, __shfl_xor(mx, 4, 64));
        mx = fmaxf(mx, __shfl_xor(mx, 8, 64));
        float se = __expf(v[0] - mx) + __expf(v[1] - mx) +
                   __expf(v[2] - mx) + __expf(v[3] - mx);
        se += __shfl_xor(se, 1, 64);
        se += __shfl_xor(se, 2, 64);
        se += __shfl_xor(se, 4, 64);
        se += __shfl_xor(se, 8, 64);
        if (fr == 0) {
          float2* pp = (float2*)partials;
          pp[(size_t)rowg * pstride + nIdx * 2 + (w & 1)] =
              make_float2(mx, se);
        }
      }
    }
  }
}

// ---------------------------------------------------------------------------
__global__ __launch_bounds__(256) void cvt_bf16_kernel(
    const float* __restrict__ src, unsigned short* __restrict__ dst) {
  size_t i = ((size_t)blockIdx.x * 256 + threadIdx.x) * 8;
  float4 a = *(const float4*)&src[i];
  float4 b = *(const float4*)&src[i + 4];
  ushort4 lo, hi;
  lo.x = f2bf(a.x); lo.y = f2bf(a.y); lo.z = f2bf(a.z); lo.w = f2bf(a.w);
  hi.x = f2bf(b.x); hi.y = f2bf(b.y); hi.z = f2bf(b.z); hi.w = f2bf(b.w);
  *(ushort4*)&dst[i] = lo;
  *(ushort4*)&dst[i + 4] = hi;
}

__global__ __launch_bounds__(256) void cvt_split_wih(
    const float* __restrict__ w_ih, unsigned short* __restrict__ Wemb,
    unsigned short* __restrict__ Wctx) {
  size_t base = ((size_t)blockIdx.x * 256 + threadIdx.x) * 8;
  int row = (int)(base >> 11);
  int col = (int)(base & 2047);
  float4 a = *(const float4*)&w_ih[base];
  float4 b = *(const float4*)&w_ih[base + 4];
  ushort4 lo, hi;
  lo.x = f2bf(a.x); lo.y = f2bf(a.y); lo.z = f2bf(a.z); lo.w = f2bf(a.w);
  hi.x = f2bf(b.x); hi.y = f2bf(b.y); hi.z = f2bf(b.z); hi.w = f2bf(b.w);
  unsigned short* dst = (col < H) ? (Wemb + (size_t)row * H + col)
                                  : (Wctx + (size_t)row * H + col - H);
  *(ushort4*)dst = lo;
  *(ushort4*)(dst + 4) = hi;
}

__global__ __launch_bounds__(256) void build_fused_bias(
    const float* __restrict__ Wa_b, const float* __restrict__ b_hh,
    float* __restrict__ fb) {
  int i = blockIdx.x * 256 + threadIdx.x;
  fb[i] = (i < H) ? Wa_b[i] : b_hh[i - H];
}

__global__ __launch_bounds__(256) void embed_all_kernel(
    const int* __restrict__ target, const float* __restrict__ emb,
    unsigned short* __restrict__ embAll) {
  int idx = blockIdx.x * 256 + threadIdx.x;  // over T*B*(H/8)
  int h8 = (idx & 127) * 8;
  int tb = idx >> 7;
  int t = tb >> 8;
  int b = tb & 255;
  int tok = (t == 0) ? 0 : target[b * T + (t - 1)];
  const float* e = emb + (size_t)tok * H + h8;
  float4 a = *(const float4*)e;
  float4 c = *(const float4*)(e + 4);
  ushort4 lo, hi;
  lo.x = f2bf(a.x); lo.y = f2bf(a.y); lo.z = f2bf(a.z); lo.w = f2bf(a.w);
  hi.x = f2bf(c.x); hi.y = f2bf(c.y); hi.z = f2bf(c.z); hi.w = f2bf(c.w);
  unsigned short* d = embAll + (size_t)tb * H + h8;
  *(ushort4*)d = lo;
  *(ushort4*)(d + 4) = hi;
}

// ---------------------------------------------------------------------------
// Fused attention: scores -> softmax -> ctx, one block per b.
// ---------------------------------------------------------------------------
__global__ __launch_bounds__(256) void attn_fused_kernel(
    const float* __restrict__ wqgh, const unsigned short* __restrict__ Uk_bf,
    const unsigned short* __restrict__ keys_bf,
    const float* __restrict__ Va_w, const float* __restrict__ Va_b,
    float* __restrict__ out_attn, unsigned short* __restrict__ ctx_bf, int t) {
  const int b = blockIdx.x;
  const int tid = threadIdx.x;
  __shared__ float wqs[H];
  __shared__ float vas[H];
  __shared__ float sw[S];

  ((float4*)wqs)[tid] = ((const float4*)(wqgh + (size_t)b * 4 * H))[tid];
  ((float4*)vas)[tid] = ((const float4*)Va_w)[tid];
  __syncthreads();

  const int s = tid >> 2;
  const int hc = (tid & 3) * 256;
  const unsigned short* uk = Uk_bf + ((size_t)b * S + s) * H + hc;
  float sum = 0.f;
#pragma unroll 4
  for (int i = 0; i < 256; i += 8) {
    bf16x8 u = *(const bf16x8*)&uk[i];
#pragma unroll
    for (int j = 0; j < 8; ++j) {
      float e = fast_tanh(wqs[hc + i + j] + bf2f((unsigned short)u[j]));
      sum += e * vas[hc + i + j];
    }
  }
  sum += __shfl_xor(sum, 1, 64);
  sum += __shfl_xor(sum, 2, 64);
  if ((tid & 3) == 0) sw[s] = sum + Va_b[0];
  __syncthreads();

  if (tid < 64) {
    float v = sw[tid];
    float m = v;
    for (int off = 32; off > 0; off >>= 1) m = fmaxf(m, __shfl_xor(m, off, 64));
    float e = __expf(v - m);
    float sm = e;
    for (int off = 32; off > 0; off >>= 1) sm += __shfl_xor(sm, off, 64);
    float wv = e / sm;
    sw[tid] = wv;
    out_attn[((size_t)b * T + t) * S + tid] = wv;
  }
  __syncthreads();

  const unsigned short* kb = keys_bf + (size_t)b * S * H + tid * 4;
  float c0 = 0.f, c1 = 0.f, c2 = 0.f, c3 = 0.f;
#pragma unroll 8
  for (int s2 = 0; s2 < S; ++s2) {
    float wv = sw[s2];
    ushort4 kv = *(const ushort4*)&kb[(size_t)s2 * H];
    c0 += wv * bf2f(kv.x);
    c1 += wv * bf2f(kv.y);
    c2 += wv * bf2f(kv.z);
    c3 += wv * bf2f(kv.w);
  }
  ushort4 o;
  o.x = f2bf(c0); o.y = f2bf(c1); o.z = f2bf(c2); o.w = f2bf(c3);
  *(ushort4*)&ctx_bf[(size_t)b * H + tid * 4] = o;
}

// ---------------------------------------------------------------------------
__global__ __launch_bounds__(256) void gru_kernel(
    const float* __restrict__ gi, const float* __restrict__ wqgh,
    const float* __restrict__ h_in, float* __restrict__ h_out,
    unsigned short* __restrict__ h_out_bf) {
  int idx = blockIdx.x * 256 + threadIdx.x;
  int b = idx >> 10;
  int j = idx & (H - 1);
  const float* gib = gi + (size_t)b * 3 * H;
  const float* ghb = wqgh + (size_t)b * 4 * H + H;
  float r = fast_sigmoid(gib[j] + ghb[j]);
  float z = fast_sigmoid(gib[H + j] + ghb[H + j]);
  float n = fast_tanh(gib[2 * H + j] + r * ghb[2 * H + j]);
  float hp = h_in[idx];
  float ho = (1.f - z) * n + z * hp;
  h_out[idx] = ho;
  h_out_bf[idx] = f2bf(ho);
}

// ---------------------------------------------------------------------------
// batched log-softmax: reduce partials -> ls[row] for all T*B rows
// ---------------------------------------------------------------------------
__global__ __launch_bounds__(256) void logsm_reduce_kernel(
    const float* __restrict__ partials, float* __restrict__ ls, int P) {
  const int row = blockIdx.x;
  const int tid = threadIdx.x;
  const float2* pp = (const float2*)partials + (size_t)row * P;
  __shared__ float red[256];
  float mx = -INFINITY;
  for (int i = tid; i < P; i += 256) mx = fmaxf(mx, pp[i].x);
  red[tid] = mx;
  __syncthreads();
  for (int off = 128; off > 0; off >>= 1) {
    if (tid < off) red[tid] = fmaxf(red[tid], red[tid + off]);
    __syncthreads();
  }
  mx = red[0];
  __syncthreads();
  float sm = 0.f;
  for (int i = tid; i < P; i += 256) sm += pp[i].y * __expf(pp[i].x - mx);
  red[tid] = sm;
  __syncthreads();
  for (int off = 128; off > 0; off >>= 1) {
    if (tid < off) red[tid] += red[tid + off];
    __syncthreads();
  }
  if (tid == 0) ls[row] = mx + __logf(red[0]);
}

// dec[b, t, :] = bf2f(logits_bf[tb, :]) - ls[tb];  tb = t*B + b
__global__ __launch_bounds__(256) void logsm_sub_kernel(
    const unsigned short* __restrict__ logits_bf, const float* __restrict__ ls,
    float* __restrict__ dec) {
  const int tb = blockIdx.y;
  const int t = tb >> 8;         // B = 256
  const int b = tb & 255;
  const int i8 = (blockIdx.x * 256 + threadIdx.x) * 8;
  if (i8 < V) {
    float l = ls[tb];
    const unsigned short* src = logits_bf + (size_t)tb * V + i8;
    bf16x8 u = *(const bf16x8*)src;
    float* d = dec + (size_t)b * T * V + (size_t)t * V + i8;
    float4 o0, o1;
    o0.x = bf2f((unsigned short)u[0]) - l; o0.y = bf2f((unsigned short)u[1]) - l;
    o0.z = bf2f((unsigned short)u[2]) - l; o0.w = bf2f((unsigned short)u[3]) - l;
    o1.x = bf2f((unsigned short)u[4]) - l; o1.y = bf2f((unsigned short)u[5]) - l;
    o1.z = bf2f((unsigned short)u[6]) - l; o1.w = bf2f((unsigned short)u[7]) - l;
    *(float4*)d = o0;
    *(float4*)(d + 4) = o1;
  }
}

__global__ __launch_bounds__(256) void copy_kernel(
    const float* __restrict__ src, float* __restrict__ dst, int n) {
  int i = blockIdx.x * 256 + threadIdx.x;
  if (i < n) dst[i] = src[i];
}

// ---------------------------------------------------------------------------
extern "C" void kernel_launch(void* const* d_in, const int* in_sizes, int n_in,
                              void* d_out, int out_size, void* d_ws, size_t ws_size,
                              hipStream_t stream) {
  const float* keys       = (const float*)d_in[0];
  const float* enc_hidden = (const float*)d_in[1];
  const int*   target     = (const int*)d_in[2];
  const float* embedding  = (const float*)d_in[3];
  const float* Wa_w = (const float*)d_in[4];
  const float* Wa_b = (const float*)d_in[5];
  const float* Ua_w = (const float*)d_in[6];
  const float* Ua_b = (const float*)d_in[7];
  const float* Va_w = (const float*)d_in[8];
  const float* Va_b = (const float*)d_in[9];
  const float* gru_w_ih = (const float*)d_in[10];
  const float* gru_w_hh = (const float*)d_in[11];
  const float* gru_b_ih = (const float*)d_in[12];
  const float* gru_b_hh = (const float*)d_in[13];
  const float* out_w = (const float*)d_in[14];
  const float* out_b = (const float*)d_in[15];

  float* out = (float*)d_out;
  float* out_dec  = out;
  float* out_h    = out + (size_t)B * T * V;
  float* out_attn = out + (size_t)B * T * V + (size_t)B * H;

  // ---- workspace ----
  char* p = (char*)d_ws;
  unsigned short* keys_bf = (unsigned short*)p; p += (size_t)B * S * H * 2;
  unsigned short* outw_bf = (unsigned short*)p; p += (size_t)V * H * 2;
  unsigned short* Uaw_bf  = (unsigned short*)p; p += (size_t)H * H * 2;
  unsigned short* fusedW  = (unsigned short*)p; p += (size_t)4 * H * H * 2;
  float*          fusedB  = (float*)p;          p += (size_t)4 * H * 4;
  unsigned short* Wemb_bf = (unsigned short*)p; p += (size_t)3 * H * H * 2;
  unsigned short* Wctx_bf = (unsigned short*)p; p += (size_t)3 * H * H * 2;
  unsigned short* embAll  = (unsigned short*)p; p += (size_t)T * B * H * 2;
  unsigned short* Uk_bf   = (unsigned short*)p; p += (size_t)B * S * H * 2;
  float*          giE     = (float*)p;          p += (size_t)T * B * 3 * H * 4;
  float*          wqgh    = (float*)p;          p += (size_t)B * 4 * H * 4;
  unsigned short* ctx_bf  = (unsigned short*)p; p += (size_t)B * H * 2;
  float*          gi      = (float*)p;          p += (size_t)B * 3 * H * 4;
  float*          hA      = (float*)p;          p += (size_t)B * H * 4;
  float*          hB      = (float*)p;          p += (size_t)B * H * 4;
  unsigned short* hAll    = (unsigned short*)p; p += (size_t)(T + 1) * B * H * 2;
  unsigned short* logits_bf = (unsigned short*)p; p += (size_t)T * B * V * 2;
  float*          parts   = (float*)p;          p += (size_t)T * B * 500 * 2 * 4;
  float*          ls      = (float*)p;          p += (size_t)T * B * 4;

  // ---- one-time prep ----
  cvt_bf16_kernel<<<(B * S * H) / 2048, 256, 0, stream>>>(keys, keys_bf);
  cvt_bf16_kernel<<<((size_t)V * H) / 2048, 256, 0, stream>>>(out_w, outw_bf);
  cvt_bf16_kernel<<<(H * H) / 2048, 256, 0, stream>>>(Ua_w, Uaw_bf);
  cvt_bf16_kernel<<<(H * H) / 2048, 256, 0, stream>>>(Wa_w, fusedW);
  cvt_bf16_kernel<<<(3 * H * H) / 2048, 256, 0, stream>>>(gru_w_hh,
                                                          fusedW + (size_t)H * H);
  build_fused_bias<<<(4 * H) / 256, 256, 0, stream>>>(Wa_b, gru_b_hh, fusedB);
  cvt_split_wih<<<(3 * H * 2 * H) / 2048, 256, 0, stream>>>(gru_w_ih, Wemb_bf,
                                                            Wctx_bf);
  embed_all_kernel<<<(T * B * H / 8) / 256, 256, 0, stream>>>(target, embedding,
                                                              embAll);
  cvt_bf16_kernel<<<(B * H) / 2048, 256, 0, stream>>>(enc_hidden, hAll);

  // Uk_bf = bf16(keys @ Ua_w^T + Ua_b)   (TM=256: M=16384 -> 64 m-tiles)
  gemm_mfma<256, 128, 1, 1, 2>
      <<<dim3((B * S) / 256, H / 128), 256, 0, stream>>>(
          keys_bf, Uaw_bf, Ua_b, nullptr, Uk_bf, nullptr, B * S, H, H, H, 0);
  // giE = embAll @ Wemb^T + b_ih
  gemm_mfma<128, 128, 0, 1, 2>
      <<<dim3((T * B) / 128, 3 * H / 128), 256, 0, stream>>>(
          embAll, Wemb_bf, gru_b_ih, giE, nullptr, nullptr, T * B, 3 * H, H,
          3 * H, 0);

  const float* h_in = enc_hidden;
  float* hbufs[2] = {hA, hB};

  for (int t = 0; t < T; ++t) {
    const unsigned short* hbf_in = hAll + (size_t)t * B * H;
    unsigned short* hbf_out = hAll + (size_t)(t + 1) * B * H;
    float* h_out = hbufs[t & 1];

    // wq | gh = h @ [Wa_w; w_hh]^T + [Wa_b; b_hh]
    gemm_mfma<64, 64, 0, 1, 3><<<dim3(B / 64, 4 * H / 64), 256, 0, stream>>>(
        hbf_in, fusedW, fusedB, wqgh, nullptr, nullptr, B, 4 * H, H, 4 * H, 0);
    attn_fused_kernel<<<B, 256, 0, stream>>>(
        wqgh, Uk_bf, keys_bf, Va_w, Va_b, out_attn, ctx_bf, t);
    // gi = giE[t] + ctx @ Wctx^T
    gemm_mfma<64, 64, 2, 1, 3><<<dim3(B / 64, 3 * H / 64), 256, 0, stream>>>(
        ctx_bf, Wctx_bf, giE + (size_t)t * B * 3 * H, gi, nullptr, nullptr,
        B, 3 * H, H, 3 * H, 0);
    gru_kernel<<<(B * H) / 256, 256, 0, stream>>>(gi, wqgh, h_in, h_out,
                                                  hbf_out);

    h_in = h_out;
  }

  // batched vocab projection over all steps (TM=256: 10 m-tiles x 250 n-tiles)
  gemm_mfma<256, 128, 3, 1, 2>
      <<<dim3((T * B) / 256, V / 128), 256, 0, stream>>>(
          hAll + (size_t)B * H, outw_bf, out_b, nullptr, logits_bf, parts,
          T * B, V, H, V, 500);
  logsm_reduce_kernel<<<T * B, 256, 0, stream>>>(parts, ls, 500);
  logsm_sub_kernel<<<dim3((V + 2047) / 2048, T * B), 256, 0, stream>>>(
      logits_bf, ls, out_dec);

  copy_kernel<<<(B * H + 255) / 256, 256, 0, stream>>>(h_in, out_h, B * H);
}

// Round 11
// 1019.658 us; speedup vs baseline: 2.7177x; 1.1919x over previous
//
#include <hip/hip_runtime.h>
#include <math.h>

#define H 1024
#define V 32000
#define B 256
#define S 64
#define T 10

#define GBK 32

typedef __attribute__((ext_vector_type(8))) short bf16x8;
typedef __attribute__((ext_vector_type(4))) float f32x4;

static __device__ __forceinline__ unsigned short f2bf(float f) {
  unsigned int u = __float_as_uint(f);
  u += 0x7fff + ((u >> 16) & 1);   // round-to-nearest-even
  return (unsigned short)(u >> 16);
}
static __device__ __forceinline__ float bf2f(unsigned short u) {
  return __uint_as_float(((unsigned int)u) << 16);
}
static __device__ __forceinline__ float fast_tanh(float x) {
  float e = __expf(2.f * x);
  return 1.f - 2.f * __builtin_amdgcn_rcpf(e + 1.f);
}
static __device__ __forceinline__ float fast_sigmoid(float x) {
  return __builtin_amdgcn_rcpf(1.f + __expf(-x));
}

static __device__ __forceinline__ void load_lds16(const void* g, void* l) {
  __builtin_amdgcn_global_load_lds(
      (const __attribute__((address_space(1))) unsigned int*)g,
      (__attribute__((address_space(3))) unsigned int*)l, 16, 0, 0);
}

// swizzled element offset within one LDS tile: row stride 32 elems (64 B).
static __device__ __forceinline__ int lds_off(int row, int g) {
  return row * GBK + ((g ^ ((row >> 1) & 3)) * 8);
}

// ---------------------------------------------------------------------------
// bf16 MFMA GEMM, TMxTN tile, BK=32, 4 waves (2x2), STAGES-deep pipeline with
// counted vmcnt + raw barrier.  C = A @ W^T (+ epilogue).
// F = STAGES-2 stages stay in flight across barriers (F=0 for STAGES=2).
// Steady state: wait vmcnt(F*LOADS) -> stage t landed; barrier publishes it;
// restage buffer (t+F+1)%STAGES (== buffer consumed at t-1, safe after bar).
// GRIDMODE 0: grid (N/TN, M/TM).
// GRIDMODE 1: grid (M/TM, N/TN) + bijective XCD swizzle (m204): each XCD owns
//   a contiguous chunk of N-panels, M varies fastest -> W panel L2-resident.
// MODE 0: C fp32 = acc + bias[col]
// MODE 1: Cb bf16 = acc + bias[col]
// MODE 2: C fp32 = acc + aux[row*ldc + col]
// MODE 3: Cb bf16 = acc + bias[col]; per-row (max,sumexp) partials ->
//         partials[row][nIdx*2 + (w&1)]                (TN=128 only)
// ---------------------------------------------------------------------------
template <int TM, int TN, int MODE, int GRIDMODE, int STAGES>
__global__ __launch_bounds__(256) void gemm_mfma(
    const unsigned short* __restrict__ A, const unsigned short* __restrict__ W,
    const float* __restrict__ aux, float* __restrict__ C,
    unsigned short* __restrict__ Cb, float* __restrict__ partials,
    int M, int N, int K, int ldc, int pstride) {
  constexpr int FM = TM / 32;
  constexpr int FN = TN / 32;
  constexpr int CA = TM / 64;
  constexpr int CB = TN / 64;
  constexpr int LOADS = CA + CB;
  constexpr int F = (STAGES >= 3) ? (STAGES - 2) : 0;

  __shared__ unsigned short lsA[STAGES][TM * GBK];
  __shared__ unsigned short lsB[STAGES][TN * GBK];
  const int tid = threadIdx.x;
  const int lane = tid & 63;
  const int w = tid >> 6;

  int mIdx, nIdx;
  if constexpr (GRIDMODE == 1) {
    const int nwg = gridDim.x * gridDim.y;
    const int orig = blockIdx.y * gridDim.x + blockIdx.x;
    const int q = nwg >> 3, rr = nwg & 7;
    const int xcd = orig & 7, rest = orig >> 3;
    const int wgid =
        (xcd < rr ? xcd * (q + 1) : rr * (q + 1) + (xcd - rr) * q) + rest;
    mIdx = wgid % gridDim.x;
    nIdx = wgid / gridDim.x;
  } else {
    mIdx = blockIdx.y;
    nIdx = blockIdx.x;
  }
  const int mBase = mIdx * TM;
  const int nBase = nIdx * TN;
  const int rowBase = (w >> 1) * (TM / 2);
  const int colBase = (w & 1) * (TN / 2);

  const int fr = lane & 15;
  const int fkU = lane >> 4;
  const int fg = lane >> 4;

  f32x4 acc[FM][FN] = {};

  auto STAGE = [&](int buf, int k0) {
#pragma unroll
    for (int i = 0; i < CA; ++i) {
      int chunk = i * 256 + tid;
      int row = chunk >> 2;
      int u = chunk & 3;
      int col = (u ^ ((row >> 1) & 3)) * 8;
      load_lds16(A + (size_t)(mBase + row) * K + k0 + col,
                 &lsA[buf][chunk * 8]);
    }
#pragma unroll
    for (int i = 0; i < CB; ++i) {
      int chunk = i * 256 + tid;
      int row = chunk >> 2;
      int u = chunk & 3;
      int col = (u ^ ((row >> 1) & 3)) * 8;
      load_lds16(W + (size_t)(nBase + row) * K + k0 + col,
                 &lsB[buf][chunk * 8]);
    }
  };

  const int NT = K / GBK;
  for (int s = 0; s <= F && s < NT; ++s) STAGE(s % STAGES, s * GBK);

  for (int t = 0; t < NT; ++t) {
    const int rem = NT - 1 - t;  // stages still outstanding beyond t (<= F)
    if (rem >= F) {
      asm volatile("s_waitcnt vmcnt(%0)\n\ts_barrier" :: "i"(F * LOADS)
                   : "memory");
    } else if (rem == 2) {
      asm volatile("s_waitcnt vmcnt(%0)\n\ts_barrier" :: "i"(2 * LOADS)
                   : "memory");
    } else if (rem == 1) {
      asm volatile("s_waitcnt vmcnt(%0)\n\ts_barrier" :: "i"(1 * LOADS)
                   : "memory");
    } else {
      asm volatile("s_waitcnt vmcnt(0)\n\ts_barrier" ::: "memory");
    }
    if (t + F + 1 < NT) STAGE((t + F + 1) % STAGES, (t + F + 1) * GBK);

    const int cb = t % STAGES;
    bf16x8 af[FM], bfr[FN];
#pragma unroll
    for (int m = 0; m < FM; ++m)
      af[m] = *(const bf16x8*)&lsA[cb][lds_off(rowBase + m * 16 + fr, fkU)];
#pragma unroll
    for (int n = 0; n < FN; ++n)
      bfr[n] = *(const bf16x8*)&lsB[cb][lds_off(colBase + n * 16 + fr, fkU)];
#pragma unroll
    for (int m = 0; m < FM; ++m)
#pragma unroll
      for (int n = 0; n < FN; ++n)
        acc[m][n] = __builtin_amdgcn_mfma_f32_16x16x32_bf16(
            af[m], bfr[n], acc[m][n], 0, 0, 0);
  }

#pragma unroll
  for (int m = 0; m < FM; ++m) {
    int colg[FN];
    float bv[FN];
#pragma unroll
    for (int n = 0; n < FN; ++n) {
      colg[n] = nBase + colBase + n * 16 + fr;
      if constexpr (MODE != 2) bv[n] = aux[colg[n]];
    }
#pragma unroll
    for (int r = 0; r < 4; ++r) {
      const int rowg = mBase + rowBase + m * 16 + fg * 4 + r;
      float v[FN];
#pragma unroll
      for (int n = 0; n < FN; ++n) {
        if constexpr (MODE == 2)
          v[n] = acc[m][n][r] + aux[(size_t)rowg * ldc + colg[n]];
        else
          v[n] = acc[m][n][r] + bv[n];
        if constexpr (MODE == 1 || MODE == 3)
          Cb[(size_t)rowg * ldc + colg[n]] = f2bf(v[n]);
        else
          C[(size_t)rowg * ldc + colg[n]] = v[n];
      }
      if constexpr (MODE == 3) {
        float mx = fmaxf(fmaxf(v[0], v[1]), fmaxf(v[2], v[3]));
        mx = fmaxf(mx, __shfl_xor(mx, 1, 64));
        mx = fmaxf(mx, __shfl_xor(mx, 2, 64));
        mx = fmaxf(mx, __shfl_xor(mx, 4, 64));
        mx = fmaxf(mx, __shfl_xor(mx, 8, 64));
        float se = __expf(v[0] - mx) + __expf(v[1] - mx) +
                   __expf(v[2] - mx) + __expf(v[3] - mx);
        se += __shfl_xor(se, 1, 64);
        se += __shfl_xor(se, 2, 64);
        se += __shfl_xor(se, 4, 64);
        se += __shfl_xor(se, 8, 64);
        if (fr == 0) {
          float2* pp = (float2*)partials;
          pp[(size_t)rowg * pstride + nIdx * 2 + (w & 1)] =
              make_float2(mx, se);
        }
      }
    }
  }
}

// ---------------------------------------------------------------------------
__global__ __launch_bounds__(256) void cvt_bf16_kernel(
    const float* __restrict__ src, unsigned short* __restrict__ dst) {
  size_t i = ((size_t)blockIdx.x * 256 + threadIdx.x) * 8;
  float4 a = *(const float4*)&src[i];
  float4 b = *(const float4*)&src[i + 4];
  ushort4 lo, hi;
  lo.x = f2bf(a.x); lo.y = f2bf(a.y); lo.z = f2bf(a.z); lo.w = f2bf(a.w);
  hi.x = f2bf(b.x); hi.y = f2bf(b.y); hi.z = f2bf(b.z); hi.w = f2bf(b.w);
  *(ushort4*)&dst[i] = lo;
  *(ushort4*)&dst[i + 4] = hi;
}

__global__ __launch_bounds__(256) void cvt_split_wih(
    const float* __restrict__ w_ih, unsigned short* __restrict__ Wemb,
    unsigned short* __restrict__ Wctx) {
  size_t base = ((size_t)blockIdx.x * 256 + threadIdx.x) * 8;
  int row = (int)(base >> 11);
  int col = (int)(base & 2047);
  float4 a = *(const float4*)&w_ih[base];
  float4 b = *(const float4*)&w_ih[base + 4];
  ushort4 lo, hi;
  lo.x = f2bf(a.x); lo.y = f2bf(a.y); lo.z = f2bf(a.z); lo.w = f2bf(a.w);
  hi.x = f2bf(b.x); hi.y = f2bf(b.y); hi.z = f2bf(b.z); hi.w = f2bf(b.w);
  unsigned short* dst = (col < H) ? (Wemb + (size_t)row * H + col)
                                  : (Wctx + (size_t)row * H + col - H);
  *(ushort4*)dst = lo;
  *(ushort4*)(dst + 4) = hi;
}

__global__ __launch_bounds__(256) void build_fused_bias(
    const float* __restrict__ Wa_b, const float* __restrict__ b_hh,
    float* __restrict__ fb) {
  int i = blockIdx.x * 256 + threadIdx.x;
  fb[i] = (i < H) ? Wa_b[i] : b_hh[i - H];
}

__global__ __launch_bounds__(256) void embed_all_kernel(
    const int* __restrict__ target, const float* __restrict__ emb,
    unsigned short* __restrict__ embAll) {
  int idx = blockIdx.x * 256 + threadIdx.x;  // over T*B*(H/8)
  int h8 = (idx & 127) * 8;
  int tb = idx >> 7;
  int t = tb >> 8;
  int b = tb & 255;
  int tok = (t == 0) ? 0 : target[b * T + (t - 1)];
  const float* e = emb + (size_t)tok * H + h8;
  float4 a = *(const float4*)e;
  float4 c = *(const float4*)(e + 4);
  ushort4 lo, hi;
  lo.x = f2bf(a.x); lo.y = f2bf(a.y); lo.z = f2bf(a.z); lo.w = f2bf(a.w);
  hi.x = f2bf(c.x); hi.y = f2bf(c.y); hi.z = f2bf(c.z); hi.w = f2bf(c.w);
  unsigned short* d = embAll + (size_t)tb * H + h8;
  *(ushort4*)d = lo;
  *(ushort4*)(d + 4) = hi;
}

// ---------------------------------------------------------------------------
// Fused attention: scores -> softmax -> ctx, one block per b.
// ---------------------------------------------------------------------------
__global__ __launch_bounds__(256) void attn_fused_kernel(
    const float* __restrict__ wqgh, const unsigned short* __restrict__ Uk_bf,
    const unsigned short* __restrict__ keys_bf,
    const float* __restrict__ Va_w, const float* __restrict__ Va_b,
    float* __restrict__ out_attn, unsigned short* __restrict__ ctx_bf, int t) {
  const int b = blockIdx.x;
  const int tid = threadIdx.x;
  __shared__ float wqs[H];
  __shared__ float vas[H];
  __shared__ float sw[S];

  ((float4*)wqs)[tid] = ((const float4*)(wqgh + (size_t)b * 4 * H))[tid];
  ((float4*)vas)[tid] = ((const float4*)Va_w)[tid];
  __syncthreads();

  const int s = tid >> 2;
  const int hc = (tid & 3) * 256;
  const unsigned short* uk = Uk_bf + ((size_t)b * S + s) * H + hc;
  float sum = 0.f;
#pragma unroll 4
  for (int i = 0; i < 256; i += 8) {
    bf16x8 u = *(const bf16x8*)&uk[i];
#pragma unroll
    for (int j = 0; j < 8; ++j) {
      float e = fast_tanh(wqs[hc + i + j] + bf2f((unsigned short)u[j]));
      sum += e * vas[hc + i + j];
    }
  }
  sum += __shfl_xor(sum, 1, 64);
  sum += __shfl_xor(sum, 2, 64);
  if ((tid & 3) == 0) sw[s] = sum + Va_b[0];
  __syncthreads();

  if (tid < 64) {
    float v = sw[tid];
    float m = v;
    for (int off = 32; off > 0; off >>= 1) m = fmaxf(m, __shfl_xor(m, off, 64));
    float e = __expf(v - m);
    float sm = e;
    for (int off = 32; off > 0; off >>= 1) sm += __shfl_xor(sm, off, 64);
    float wv = e / sm;
    sw[tid] = wv;
    out_attn[((size_t)b * T + t) * S + tid] = wv;
  }
  __syncthreads();

  const unsigned short* kb = keys_bf + (size_t)b * S * H + tid * 4;
  float c0 = 0.f, c1 = 0.f, c2 = 0.f, c3 = 0.f;
#pragma unroll 8
  for (int s2 = 0; s2 < S; ++s2) {
    float wv = sw[s2];
    ushort4 kv = *(const ushort4*)&kb[(size_t)s2 * H];
    c0 += wv * bf2f(kv.x);
    c1 += wv * bf2f(kv.y);
    c2 += wv * bf2f(kv.z);
    c3 += wv * bf2f(kv.w);
  }
  ushort4 o;
  o.x = f2bf(c0); o.y = f2bf(c1); o.z = f2bf(c2); o.w = f2bf(c3);
  *(ushort4*)&ctx_bf[(size_t)b * H + tid * 4] = o;
}

// ---------------------------------------------------------------------------
__global__ __launch_bounds__(256) void gru_kernel(
    const float* __restrict__ gi, const float* __restrict__ wqgh,
    const float* __restrict__ h_in, float* __restrict__ h_out,
    unsigned short* __restrict__ h_out_bf) {
  int idx = blockIdx.x * 256 + threadIdx.x;
  int b = idx >> 10;
  int j = idx & (H - 1);
  const float* gib = gi + (size_t)b * 3 * H;
  const float* ghb = wqgh + (size_t)b * 4 * H + H;
  float r = fast_sigmoid(gib[j] + ghb[j]);
  float z = fast_sigmoid(gib[H + j] + ghb[H + j]);
  float n = fast_tanh(gib[2 * H + j] + r * ghb[2 * H + j]);
  float hp = h_in[idx];
  float ho = (1.f - z) * n + z * hp;
  h_out[idx] = ho;
  h_out_bf[idx] = f2bf(ho);
}

// ---------------------------------------------------------------------------
// batched log-softmax: reduce partials -> ls[row] for all T*B rows
// ---------------------------------------------------------------------------
__global__ __launch_bounds__(256) void logsm_reduce_kernel(
    const float* __restrict__ partials, float* __restrict__ ls, int P) {
  const int row = blockIdx.x;
  const int tid = threadIdx.x;
  const float2* pp = (const float2*)partials + (size_t)row * P;
  __shared__ float red[256];
  float mx = -INFINITY;
  for (int i = tid; i < P; i += 256) mx = fmaxf(mx, pp[i].x);
  red[tid] = mx;
  __syncthreads();
  for (int off = 128; off > 0; off >>= 1) {
    if (tid < off) red[tid] = fmaxf(red[tid], red[tid + off]);
    __syncthreads();
  }
  mx = red[0];
  __syncthreads();
  float sm = 0.f;
  for (int i = tid; i < P; i += 256) sm += pp[i].y * __expf(pp[i].x - mx);
  red[tid] = sm;
  __syncthreads();
  for (int off = 128; off > 0; off >>= 1) {
    if (tid < off) red[tid] += red[tid + off];
    __syncthreads();
  }
  if (tid == 0) ls[row] = mx + __logf(red[0]);
}

// dec[b, t, :] = bf2f(logits_bf[tb, :]) - ls[tb];  tb = t*B + b
__global__ __launch_bounds__(256) void logsm_sub_kernel(
    const unsigned short* __restrict__ logits_bf, const float* __restrict__ ls,
    float* __restrict__ dec) {
  const int tb = blockIdx.y;
  const int t = tb >> 8;         // B = 256
  const int b = tb & 255;
  const int i8 = (blockIdx.x * 256 + threadIdx.x) * 8;
  if (i8 < V) {
    float l = ls[tb];
    const unsigned short* src = logits_bf + (size_t)tb * V + i8;
    bf16x8 u = *(const bf16x8*)src;
    float* d = dec + (size_t)b * T * V + (size_t)t * V + i8;
    float4 o0, o1;
    o0.x = bf2f((unsigned short)u[0]) - l; o0.y = bf2f((unsigned short)u[1]) - l;
    o0.z = bf2f((unsigned short)u[2]) - l; o0.w = bf2f((unsigned short)u[3]) - l;
    o1.x = bf2f((unsigned short)u[4]) - l; o1.y = bf2f((unsigned short)u[5]) - l;
    o1.z = bf2f((unsigned short)u[6]) - l; o1.w = bf2f((unsigned short)u[7]) - l;
    *(float4*)d = o0;
    *(float4*)(d + 4) = o1;
  }
}

__global__ __launch_bounds__(256) void copy_kernel(
    const float* __restrict__ src, float* __restrict__ dst, int n) {
  int i = blockIdx.x * 256 + threadIdx.x;
  if (i < n) dst[i] = src[i];
}

// ---------------------------------------------------------------------------
extern "C" void kernel_launch(void* const* d_in, const int* in_sizes, int n_in,
                              void* d_out, int out_size, void* d_ws, size_t ws_size,
                              hipStream_t stream) {
  const float* keys       = (const float*)d_in[0];
  const float* enc_hidden = (const float*)d_in[1];
  const int*   target     = (const int*)d_in[2];
  const float* embedding  = (const float*)d_in[3];
  const float* Wa_w = (const float*)d_in[4];
  const float* Wa_b = (const float*)d_in[5];
  const float* Ua_w = (const float*)d_in[6];
  const float* Ua_b = (const float*)d_in[7];
  const float* Va_w = (const float*)d_in[8];
  const float* Va_b = (const float*)d_in[9];
  const float* gru_w_ih = (const float*)d_in[10];
  const float* gru_w_hh = (const float*)d_in[11];
  const float* gru_b_ih = (const float*)d_in[12];
  const float* gru_b_hh = (const float*)d_in[13];
  const float* out_w = (const float*)d_in[14];
  const float* out_b = (const float*)d_in[15];

  float* out = (float*)d_out;
  float* out_dec  = out;
  float* out_h    = out + (size_t)B * T * V;
  float* out_attn = out + (size_t)B * T * V + (size_t)B * H;

  // ---- workspace ----
  char* p = (char*)d_ws;
  unsigned short* keys_bf = (unsigned short*)p; p += (size_t)B * S * H * 2;
  unsigned short* outw_bf = (unsigned short*)p; p += (size_t)V * H * 2;
  unsigned short* Uaw_bf  = (unsigned short*)p; p += (size_t)H * H * 2;
  unsigned short* fusedW  = (unsigned short*)p; p += (size_t)4 * H * H * 2;
  float*          fusedB  = (float*)p;          p += (size_t)4 * H * 4;
  unsigned short* Wemb_bf = (unsigned short*)p; p += (size_t)3 * H * H * 2;
  unsigned short* Wctx_bf = (unsigned short*)p; p += (size_t)3 * H * H * 2;
  unsigned short* embAll  = (unsigned short*)p; p += (size_t)T * B * H * 2;
  unsigned short* Uk_bf   = (unsigned short*)p; p += (size_t)B * S * H * 2;
  float*          giE     = (float*)p;          p += (size_t)T * B * 3 * H * 4;
  float*          wqgh    = (float*)p;          p += (size_t)B * 4 * H * 4;
  unsigned short* ctx_bf  = (unsigned short*)p; p += (size_t)B * H * 2;
  float*          gi      = (float*)p;          p += (size_t)B * 3 * H * 4;
  float*          hA      = (float*)p;          p += (size_t)B * H * 4;
  float*          hB      = (float*)p;          p += (size_t)B * H * 4;
  unsigned short* hAll    = (unsigned short*)p; p += (size_t)(T + 1) * B * H * 2;
  unsigned short* logits_bf = (unsigned short*)p; p += (size_t)T * B * V * 2;
  float*          parts   = (float*)p;          p += (size_t)T * B * 500 * 2 * 4;
  float*          ls      = (float*)p;          p += (size_t)T * B * 4;

  // ---- one-time prep ----
  cvt_bf16_kernel<<<(B * S * H) / 2048, 256, 0, stream>>>(keys, keys_bf);
  cvt_bf16_kernel<<<((size_t)V * H) / 2048, 256, 0, stream>>>(out_w, outw_bf);
  cvt_bf16_kernel<<<(H * H) / 2048, 256, 0, stream>>>(Ua_w, Uaw_bf);
  cvt_bf16_kernel<<<(H * H) / 2048, 256, 0, stream>>>(Wa_w, fusedW);
  cvt_bf16_kernel<<<(3 * H * H) / 2048, 256, 0, stream>>>(gru_w_hh,
                                                          fusedW + (size_t)H * H);
  build_fused_bias<<<(4 * H) / 256, 256, 0, stream>>>(Wa_b, gru_b_hh, fusedB);
  cvt_split_wih<<<(3 * H * 2 * H) / 2048, 256, 0, stream>>>(gru_w_ih, Wemb_bf,
                                                            Wctx_bf);
  embed_all_kernel<<<(T * B * H / 8) / 256, 256, 0, stream>>>(target, embedding,
                                                              embAll);
  cvt_bf16_kernel<<<(B * H) / 2048, 256, 0, stream>>>(enc_hidden, hAll);

  // Uk_bf = bf16(keys @ Ua_w^T + Ua_b)
  gemm_mfma<128, 128, 1, 0, 2>
      <<<dim3(H / 128, (B * S) / 128), 256, 0, stream>>>(
          keys_bf, Uaw_bf, Ua_b, nullptr, Uk_bf, nullptr, B * S, H, H, H, 0);
  // giE = embAll @ Wemb^T + b_ih
  gemm_mfma<128, 128, 0, 1, 2>
      <<<dim3((T * B) / 128, 3 * H / 128), 256, 0, stream>>>(
          embAll, Wemb_bf, gru_b_ih, giE, nullptr, nullptr, T * B, 3 * H, H,
          3 * H, 0);

  const float* h_in = enc_hidden;
  float* hbufs[2] = {hA, hB};

  for (int t = 0; t < T; ++t) {
    const unsigned short* hbf_in = hAll + (size_t)t * B * H;
    unsigned short* hbf_out = hAll + (size_t)(t + 1) * B * H;
    float* h_out = hbufs[t & 1];

    // wq | gh = h @ [Wa_w; w_hh]^T + [Wa_b; b_hh]   (deep pipeline, vmcnt(6))
    gemm_mfma<64, 64, 0, 1, 5><<<dim3(B / 64, 4 * H / 64), 256, 0, stream>>>(
        hbf_in, fusedW, fusedB, wqgh, nullptr, nullptr, B, 4 * H, H, 4 * H, 0);
    attn_fused_kernel<<<B, 256, 0, stream>>>(
        wqgh, Uk_bf, keys_bf, Va_w, Va_b, out_attn, ctx_bf, t);
    // gi = giE[t] + ctx @ Wctx^T                    (deep pipeline, vmcnt(6))
    gemm_mfma<64, 64, 2, 1, 5><<<dim3(B / 64, 3 * H / 64), 256, 0, stream>>>(
        ctx_bf, Wctx_bf, giE + (size_t)t * B * 3 * H, gi, nullptr, nullptr,
        B, 3 * H, H, 3 * H, 0);
    gru_kernel<<<(B * H) / 256, 256, 0, stream>>>(gi, wqgh, h_in, h_out,
                                                  hbf_out);

    h_in = h_out;
  }

  // batched vocab projection over all steps: A rows tb = t*B + b -> h_{t+1}
  gemm_mfma<128, 128, 3, 1, 2>
      <<<dim3((T * B) / 128, V / 128), 256, 0, stream>>>(
          hAll + (size_t)B * H, outw_bf, out_b, nullptr, logits_bf, parts,
          T * B, V, H, V, 500);
  logsm_reduce_kernel<<<T * B, 256, 0, stream>>>(parts, ls, 500);
  logsm_sub_kernel<<<dim3((V + 2047) / 2048, T * B), 256, 0, stream>>>(
      logits_bf, ls, out_dec);

  copy_kernel<<<(B * H + 255) / 256, 256, 0, stream>>>(h_in, out_h, B * H);
}